// Round 5
// baseline (157.692 us; speedup 1.0000x reference)
//
#include <hip/hip_runtime.h>
#include <math.h>

// Problem constants (B=256, S=1024, V=128, T=128)
#define S_LEN 1024
#define N_ROWS (256 * 1024)   // B*S
#define T_CH 128
#define V_CH 128
#define KEEP 10
#define WT_ROWS 129           // 128 vocab rows + 1 zero row for boundaries

__device__ __forceinline__ uint32_t rotl32(uint32_t x, int r) {
    return (x << r) | (x >> (32 - r));
}

// JAX Threefry-2x32, 20 rounds, key injection schedule as in jax/_src/prng.py
__device__ __forceinline__ void threefry2x32(uint32_t k0, uint32_t k1,
                                             uint32_t x0, uint32_t x1,
                                             uint32_t& o0, uint32_t& o1) {
    uint32_t ks0 = k0, ks1 = k1, ks2 = k0 ^ k1 ^ 0x1BD11BDAu;
    x0 += ks0; x1 += ks1;
#define TF_ROUND(r) { x0 += x1; x1 = rotl32(x1, r); x1 ^= x0; }
    TF_ROUND(13) TF_ROUND(15) TF_ROUND(26) TF_ROUND(6)
    x0 += ks1; x1 += ks2 + 1u;
    TF_ROUND(17) TF_ROUND(29) TF_ROUND(16) TF_ROUND(24)
    x0 += ks2; x1 += ks0 + 2u;
    TF_ROUND(13) TF_ROUND(15) TF_ROUND(26) TF_ROUND(6)
    x0 += ks0; x1 += ks1 + 3u;
    TF_ROUND(17) TF_ROUND(29) TF_ROUND(16) TF_ROUND(24)
    x0 += ks1; x1 += ks2 + 4u;
    TF_ROUND(13) TF_ROUND(15) TF_ROUND(26) TF_ROUND(6)
    x0 += ks2; x1 += ks0 + 5u;
#undef TF_ROUND
    o0 = x0; o1 = x1;
}

// jax_threefry_partitionable=True (default since JAX 0.4.36):
// bits[n] = fold(threefry2x32(key, (hi32(n), lo32(n)))) = o0 ^ o1.
__device__ __forceinline__ uint32_t tf_bits_part(uint32_t n) {
    uint32_t o0, o1;
    threefry2x32(0u, 42u, 0u, n, o0, o1);
    return o0 ^ o1;
}

__device__ __forceinline__ float u_from_bits(uint32_t bits) {
    uint32_t m = bits >> 9;
    return (m == 0u) ? 1.17549435e-38f : (float)m * 0x1p-23f;
}

// Safe path (validated rounds 2-4): correctly-rounded f32 at each log stage
// via double-precision log. Used for keep rows and near-tie rows only.
__device__ __forceinline__ float gumbel_safe(uint32_t bits) {
    float u = u_from_bits(bits);
    float inner = (float)(-log((double)u));
    return (float)(-log((double)inner));
}

// Fast path: hardware v_log_f32 (1-ulp relative). Error <~1e-6 everywhere;
// covered by the 1e-3 top-2-gap redo guard.
__device__ __forceinline__ float gumbel_fast(uint32_t bits) {
    float u = u_from_bits(bits);
    float inner = -__logf(u);
    return -__logf(inner);
}

// ---- DPP wave64 reductions (row_shr 1/2/4/8, row_bcast 15/31, readlane 63).
// bound_ctrl=false keeps `old` on invalid source lanes; lane 63's dataflow
// only consumes valid-source lanes, so the chain is exact for max and sum.
template <int CTRL>
__device__ __forceinline__ float dpp_max_step(float v) {
    int t = __builtin_amdgcn_update_dpp(__float_as_int(v), __float_as_int(v),
                                        CTRL, 0xF, 0xF, false);
    return fmaxf(v, __int_as_float(t));
}
template <int CTRL>
__device__ __forceinline__ float dpp_add_step(float v) {
    int t = __builtin_amdgcn_update_dpp(__float_as_int(v), __float_as_int(v),
                                        CTRL, 0xF, 0xF, false);
    return v + __int_as_float(t);
}
__device__ __forceinline__ float wave_max64(float v) {
    v = dpp_max_step<0x111>(v); v = dpp_max_step<0x112>(v);
    v = dpp_max_step<0x114>(v); v = dpp_max_step<0x118>(v);
    v = dpp_max_step<0x142>(v); v = dpp_max_step<0x143>(v);
    return __int_as_float(__builtin_amdgcn_readlane(__float_as_int(v), 63));
}
__device__ __forceinline__ float wave_sum64(float v) {
    v = dpp_add_step<0x111>(v); v = dpp_add_step<0x112>(v);
    v = dpp_add_step<0x114>(v); v = dpp_add_step<0x118>(v);
    v = dpp_add_step<0x142>(v); v = dpp_add_step<0x143>(v);
    return __int_as_float(__builtin_amdgcn_readlane(__float_as_int(v), 63));
}

// wT[k][v][t]: bias folded into k=1 tap, zero row at v=128 for boundaries.
__global__ void transpose_w_kernel(const float* __restrict__ conv_w,
                                   const float* __restrict__ conv_b,
                                   float* __restrict__ wT) {
    int i = blockIdx.x * blockDim.x + threadIdx.x;  // over 3*129*128 = 49536
    if (i >= 3 * WT_ROWS * T_CH) return;
    int t = i & (T_CH - 1);
    int rest = i >> 7;
    int v = rest % WT_ROWS;
    int k = rest / WT_ROWS;
    float val = 0.0f;
    if (v < V_CH) {
        val = conv_w[t * (V_CH * 3) + v * 3 + k];
        if (k == 1) val += conv_b[t];
    }
    wT[i] = val;
}

__global__ __launch_bounds__(1024, 8) void seq_rewriter_kernel(
        const int* __restrict__ tok,
        const float* __restrict__ conv_w,
        const float* __restrict__ conv_b,
        const float* __restrict__ wT,
        float* __restrict__ out_seq,
        float* __restrict__ out_lp,
        int use_wT) {
    const int lane = threadIdx.x & 63;
    // wave id is wave-uniform: make it (and everything derived) scalar
    const int wid = __builtin_amdgcn_readfirstlane(threadIdx.x) >> 6;
    const int r = blockIdx.x * 16 + wid;         // row in [0, 262144)
    const int s = r & (S_LEN - 1);

    // scalar token loads (s_load); clamped addresses, value unused at bounds
    const int tc = tok[r];
    const int tp = tok[(s > 0) ? r - 1 : r];
    const int tn = tok[(s < S_LEN - 1) ? r + 1 : r];

    // ---- logits: lane owns classes t0 = 2*lane, t0+1 ----
    const int t0 = lane * 2;
    float l_lo, l_hi;
    if (use_wT) {
        const int vp = (s > 0) ? tp : V_CH;          // zero row at boundary
        const int vn = (s < S_LEN - 1) ? tn : V_CH;
        const float2 a = *(const float2*)(wT + 0 * (WT_ROWS * T_CH) + vp * T_CH + t0);
        const float2 b = *(const float2*)(wT + 1 * (WT_ROWS * T_CH) + tc * T_CH + t0);
        const float2 c = *(const float2*)(wT + 2 * (WT_ROWS * T_CH) + vn * T_CH + t0);
        l_lo = a.x + b.x + c.x;
        l_hi = a.y + b.y + c.y;
    } else {
        const float* wa = conv_w + (size_t)t0 * (V_CH * 3);
        const float* wb = wa + (V_CH * 3);
        l_lo = conv_b[t0];
        l_hi = conv_b[t0 + 1];
        if (s > 0)         { l_lo += wa[tp * 3 + 0]; l_hi += wb[tp * 3 + 0]; }
        l_lo += wa[tc * 3 + 1]; l_hi += wb[tc * 3 + 1];
        if (s < S_LEN - 1) { l_lo += wa[tn * 3 + 2]; l_hi += wb[tn * 3 + 2]; }
    }

    // ---- gumbel noise: partitionable threefry, bits index n = r*128 + t ----
    const uint32_t n0 = ((uint32_t)r << 7) + (uint32_t)t0;
    uint32_t b0 = tf_bits_part(n0);
    uint32_t b1 = tf_bits_part(n0 + 1u);

    // ---- fast argmax(logits + gumbel) ----
    float y0 = l_lo + gumbel_fast(b0);
    float y1 = l_hi + gumbel_fast(b1);
    float best = wave_max64(fmaxf(y0, y1));

    // redo guard: keep rows always; otherwise any second class within 1e-3
    float thr = best - 1e-3f;
    unsigned long long c0 = __ballot(y0 > thr);
    unsigned long long c1 = __ballot(y1 > thr);
    bool redo = (s < KEEP) || (__popcll(c0) + __popcll(c1) >= 2);

    int ibest;
    if (redo) {   // wave-uniform; ~1% keep rows + ~0.1% near-ties
        float ys0 = l_lo + gumbel_safe(b0);
        float ys1 = l_hi + gumbel_safe(b1);
        float yb = wave_max64(fmaxf(ys0, ys1));
        unsigned long long m0 = __ballot(ys0 == yb);
        unsigned long long m1 = __ballot(ys1 == yb);
        int i0 = m0 ? 2 * (__ffsll(m0) - 1)     : (1 << 30);
        int i1 = m1 ? 2 * (__ffsll(m1) - 1) + 1 : (1 << 30);
        ibest = min(i0, i1);
    } else {
        unsigned long long m0 = __ballot(y0 == best);
        unsigned long long m1 = __ballot(y1 == best);
        int i0 = m0 ? 2 * (__ffsll(m0) - 1)     : (1 << 30);
        int i1 = m1 ? 2 * (__ffsll(m1) - 1) + 1 : (1 << 30);
        ibest = min(i0, i1);
    }

    // ---- log_softmax at sampled action (logits tiny: no max subtraction;
    //      log_probs compared at bf16 granularity -> fast exp/log safe) ----
    float se = wave_sum64(__expf(l_lo) + __expf(l_hi));

    if (lane == (ibest >> 1)) {
        float la = (ibest & 1) ? l_hi : l_lo;
        out_lp[r] = la - __logf(se);
    }
    if (lane == 0)
        out_seq[r] = (s < KEEP) ? (float)ibest : 0.0f;
}

extern "C" void kernel_launch(void* const* d_in, const int* in_sizes, int n_in,
                              void* d_out, int out_size, void* d_ws, size_t ws_size,
                              hipStream_t stream) {
    const int* tok      = (const int*)d_in[0];     // [256,1024] int32
    const float* conv_w = (const float*)d_in[1];   // [128,128,3] f32
    const float* conv_b = (const float*)d_in[2];   // [128] f32
    float* out_seq = (float*)d_out;                // 262144 (new_seq as f32)
    float* out_lp  = (float*)d_out + N_ROWS;       // 262144 (log_probs)

    const size_t wT_bytes = (size_t)3 * WT_ROWS * T_CH * sizeof(float);
    int use_wT = (ws_size >= wT_bytes) ? 1 : 0;
    float* wT = (float*)d_ws;
    if (use_wT) {
        int n = 3 * WT_ROWS * T_CH;
        transpose_w_kernel<<<(n + 255) / 256, 256, 0, stream>>>(conv_w, conv_b, wT);
    }
    seq_rewriter_kernel<<<N_ROWS / 16, 1024, 0, stream>>>(
        tok, conv_w, conv_b, wT, out_seq, out_lp, use_wT);
}

// Round 6
// 140.108 us; speedup vs baseline: 1.1255x; 1.1255x over previous
//
#include <hip/hip_runtime.h>
#include <math.h>

// Problem constants (B=256, S=1024, V=128, T=128)
#define S_LEN 1024
#define N_ROWS (256 * 1024)   // B*S
#define T_CH 128
#define V_CH 128
#define KEEP 10
#define WT_ROWS 129           // 128 vocab rows + 1 zero row for boundaries

#define N_BLOCKS 2048
#define WAVES_PER_BLOCK 4
#define ROWS_PER_WAVE (N_ROWS / (N_BLOCKS * WAVES_PER_BLOCK))   // 32

__device__ __forceinline__ uint32_t rotl32(uint32_t x, int r) {
    return (x << r) | (x >> (32 - r));
}

// JAX Threefry-2x32, 20 rounds, key injection schedule as in jax/_src/prng.py
__device__ __forceinline__ void threefry2x32(uint32_t k0, uint32_t k1,
                                             uint32_t x0, uint32_t x1,
                                             uint32_t& o0, uint32_t& o1) {
    uint32_t ks0 = k0, ks1 = k1, ks2 = k0 ^ k1 ^ 0x1BD11BDAu;
    x0 += ks0; x1 += ks1;
#define TF_ROUND(r) { x0 += x1; x1 = rotl32(x1, r); x1 ^= x0; }
    TF_ROUND(13) TF_ROUND(15) TF_ROUND(26) TF_ROUND(6)
    x0 += ks1; x1 += ks2 + 1u;
    TF_ROUND(17) TF_ROUND(29) TF_ROUND(16) TF_ROUND(24)
    x0 += ks2; x1 += ks0 + 2u;
    TF_ROUND(13) TF_ROUND(15) TF_ROUND(26) TF_ROUND(6)
    x0 += ks0; x1 += ks1 + 3u;
    TF_ROUND(17) TF_ROUND(29) TF_ROUND(16) TF_ROUND(24)
    x0 += ks1; x1 += ks2 + 4u;
    TF_ROUND(13) TF_ROUND(15) TF_ROUND(26) TF_ROUND(6)
    x0 += ks2; x1 += ks0 + 5u;
#undef TF_ROUND
    o0 = x0; o1 = x1;
}

// jax_threefry_partitionable=True (default since JAX 0.4.36):
// bits[n] = fold(threefry2x32(key, (hi32(n), lo32(n)))) = o0 ^ o1.
__device__ __forceinline__ uint32_t tf_bits_part(uint32_t n) {
    uint32_t o0, o1;
    threefry2x32(0u, 42u, 0u, n, o0, o1);
    return o0 ^ o1;
}

// Safe path (validated rounds 2-5): exact reference semantics — tiny clamp
// and correctly-rounded f32 log stages via double log. Keep/near-tie rows only.
__device__ __forceinline__ float gumbel_safe(uint32_t bits) {
    uint32_t m = bits >> 9;
    float u = (m == 0u) ? 1.17549435e-38f : (float)m * 0x1p-23f;
    float inner = (float)(-log((double)u));
    return (float)(-log((double)inner));
}

// Fast path: hardware v_log_f32 (1-ulp relative). No m==0 clamp: m==0 gives
// y=-inf which (like the reference's ~-4.47+l) can never win the argmax.
// Flip-able near-ties are covered by the 1e-3 top-2-gap redo guard.
__device__ __forceinline__ float gumbel_fast(uint32_t bits) {
    float u = (float)(bits >> 9) * 0x1p-23f;
    float inner = -__logf(u);
    return -__logf(inner);
}

// ---- DPP wave64 reductions (row_shr 1/2/4/8, row_bcast 15/31, readlane 63).
// bound_ctrl=false keeps `old` on invalid source lanes; lane 63's dataflow
// only consumes valid-source lanes, so the chain is exact for max and sum.
template <int CTRL>
__device__ __forceinline__ float dpp_max_step(float v) {
    int t = __builtin_amdgcn_update_dpp(__float_as_int(v), __float_as_int(v),
                                        CTRL, 0xF, 0xF, false);
    return fmaxf(v, __int_as_float(t));
}
template <int CTRL>
__device__ __forceinline__ float dpp_add_step(float v) {
    int t = __builtin_amdgcn_update_dpp(__float_as_int(v), __float_as_int(v),
                                        CTRL, 0xF, 0xF, false);
    return v + __int_as_float(t);
}
__device__ __forceinline__ float wave_max64(float v) {
    v = dpp_max_step<0x111>(v); v = dpp_max_step<0x112>(v);
    v = dpp_max_step<0x114>(v); v = dpp_max_step<0x118>(v);
    v = dpp_max_step<0x142>(v); v = dpp_max_step<0x143>(v);
    return __int_as_float(__builtin_amdgcn_readlane(__float_as_int(v), 63));
}
__device__ __forceinline__ float wave_sum64(float v) {
    v = dpp_add_step<0x111>(v); v = dpp_add_step<0x112>(v);
    v = dpp_add_step<0x114>(v); v = dpp_add_step<0x118>(v);
    v = dpp_add_step<0x142>(v); v = dpp_add_step<0x143>(v);
    return __int_as_float(__builtin_amdgcn_readlane(__float_as_int(v), 63));
}

// wT[k][v][t]: bias folded into k=1 tap, zero row at v=128 for boundaries.
__global__ void transpose_w_kernel(const float* __restrict__ conv_w,
                                   const float* __restrict__ conv_b,
                                   float* __restrict__ wT) {
    int i = blockIdx.x * blockDim.x + threadIdx.x;  // over 3*129*128 = 49536
    if (i >= 3 * WT_ROWS * T_CH) return;
    int t = i & (T_CH - 1);
    int rest = i >> 7;
    int v = rest % WT_ROWS;
    int k = rest / WT_ROWS;
    float val = 0.0f;
    if (v < V_CH) {
        val = conv_w[t * (V_CH * 3) + v * 3 + k];
        if (k == 1) val += conv_b[t];
    }
    wT[i] = val;
}

__global__ __launch_bounds__(256, 8) void seq_rewriter_kernel(
        const int* __restrict__ tok,
        const float* __restrict__ wT,
        float* __restrict__ out_seq,
        float* __restrict__ out_lp) {
    const int lane = threadIdx.x & 63;
    const int wid = __builtin_amdgcn_readfirstlane(threadIdx.x >> 6);
    const int base = (blockIdx.x * WAVES_PER_BLOCK + wid) * ROWS_PER_WAVE;
    const int t0 = lane * 2;

    const float* w0t = wT;                          // k=0 (prev token)
    const float* w1t = wT + WT_ROWS * T_CH;         // k=1 (cur, bias folded)
    const float* w2t = wT + 2 * WT_ROWS * T_CH;     // k=2 (next token)

    const int s_base = base & (S_LEN - 1);          // chunk never straddles
    // rolling scalar token registers: tok[r-1], tok[r], tok[r+1]
    int tp = (s_base > 0) ? tok[base - 1] : V_CH;   // V_CH = zero row
    int tc = tok[base];

    #pragma unroll 4
    for (int i = 0; i < ROWS_PER_WAVE; ++i) {
        const int r = base + i;
        const int s = s_base + i;
        int tn = (s < S_LEN - 1) ? tok[(r + 1 < N_ROWS) ? r + 1 : r] : V_CH;

        // ---- logits for classes t0, t0+1 (scalar row bases, lane offset) ----
        const float2 a = *(const float2*)(w0t + tp * T_CH + t0);
        const float2 b = *(const float2*)(w1t + tc * T_CH + t0);
        const float2 c = *(const float2*)(w2t + tn * T_CH + t0);
        const float l_lo = a.x + b.x + c.x;
        const float l_hi = a.y + b.y + c.y;

        // ---- gumbel noise: partitionable threefry, n = r*128 + t ----
        const uint32_t n0 = ((uint32_t)r << 7) + (uint32_t)t0;
        const uint32_t bb0 = tf_bits_part(n0);
        const uint32_t bb1 = tf_bits_part(n0 + 1u);

        // ---- fast argmax(logits + gumbel) ----
        const float y0 = l_lo + gumbel_fast(bb0);
        const float y1 = l_hi + gumbel_fast(bb1);
        const float best = wave_max64(fmaxf(y0, y1));

        // redo guard: keep rows always; else any 2nd class within 1e-3
        const float thr = best - 1e-3f;
        unsigned long long c0 = __ballot(y0 > thr);
        unsigned long long c1 = __ballot(y1 > thr);
        const bool redo = (s < KEEP) || (__popcll(c0) + __popcll(c1) >= 2);

        int ibest;
        if (redo) {   // wave-uniform; ~1% keep rows + ~0.1% near-ties
            const float ys0 = l_lo + gumbel_safe(bb0);
            const float ys1 = l_hi + gumbel_safe(bb1);
            const float yb = wave_max64(fmaxf(ys0, ys1));
            unsigned long long m0 = __ballot(ys0 == yb);
            unsigned long long m1 = __ballot(ys1 == yb);
            int i0 = m0 ? 2 * (__ffsll(m0) - 1)     : (1 << 30);
            int i1 = m1 ? 2 * (__ffsll(m1) - 1) + 1 : (1 << 30);
            ibest = min(i0, i1);
        } else {
            unsigned long long m0 = __ballot(y0 == best);
            unsigned long long m1 = __ballot(y1 == best);
            int i0 = m0 ? 2 * (__ffsll(m0) - 1)     : (1 << 30);
            int i1 = m1 ? 2 * (__ffsll(m1) - 1) + 1 : (1 << 30);
            ibest = min(i0, i1);
        }

        // ---- log_softmax at sampled action (logits tiny: no max pass;
        //      log_probs compared at bf16 granularity -> fast exp/log ok) ----
        const float se = wave_sum64(__expf(l_lo) + __expf(l_hi));
        const int wl = ibest >> 1;
        const int lo_bits = __builtin_amdgcn_readlane(__float_as_int(l_lo), wl);
        const int hi_bits = __builtin_amdgcn_readlane(__float_as_int(l_hi), wl);
        const float la = __int_as_float((ibest & 1) ? hi_bits : lo_bits);
        const float lp = la - __logf(se);

        if (lane == 0) {
            out_seq[r] = (s < KEEP) ? (float)ibest : 0.0f;
            out_lp[r] = lp;
        }

        // roll tokens
        tp = tc; tc = tn;
    }
}

// Fallback (no workspace): per-row kernel reading conv_w directly.
__global__ __launch_bounds__(256) void seq_rewriter_fallback(
        const int* __restrict__ tok,
        const float* __restrict__ conv_w,
        const float* __restrict__ conv_b,
        float* __restrict__ out_seq,
        float* __restrict__ out_lp) {
    const int lane = threadIdx.x & 63;
    const int wave = threadIdx.x >> 6;
    const int r = blockIdx.x * 4 + wave;
    const int s = r & (S_LEN - 1);
    const int tc = tok[r];
    const int tp = (s > 0) ? tok[r - 1] : 0;
    const int tn = (s < S_LEN - 1) ? tok[r + 1] : 0;
    const int t0 = lane * 2;
    const float* wa = conv_w + (size_t)t0 * (V_CH * 3);
    const float* wb = wa + (V_CH * 3);
    float l_lo = conv_b[t0], l_hi = conv_b[t0 + 1];
    if (s > 0)         { l_lo += wa[tp * 3 + 0]; l_hi += wb[tp * 3 + 0]; }
    l_lo += wa[tc * 3 + 1]; l_hi += wb[tc * 3 + 1];
    if (s < S_LEN - 1) { l_lo += wa[tn * 3 + 2]; l_hi += wb[tn * 3 + 2]; }
    const uint32_t n0 = ((uint32_t)r << 7) + (uint32_t)t0;
    const uint32_t bb0 = tf_bits_part(n0);
    const uint32_t bb1 = tf_bits_part(n0 + 1u);
    const float ys0 = l_lo + gumbel_safe(bb0);
    const float ys1 = l_hi + gumbel_safe(bb1);
    float yb = wave_max64(fmaxf(ys0, ys1));
    unsigned long long m0 = __ballot(ys0 == yb);
    unsigned long long m1 = __ballot(ys1 == yb);
    int i0 = m0 ? 2 * (__ffsll(m0) - 1)     : (1 << 30);
    int i1 = m1 ? 2 * (__ffsll(m1) - 1) + 1 : (1 << 30);
    int ibest = min(i0, i1);
    const float se = wave_sum64(__expf(l_lo) + __expf(l_hi));
    const int wl = ibest >> 1;
    const int lo_bits = __builtin_amdgcn_readlane(__float_as_int(l_lo), wl);
    const int hi_bits = __builtin_amdgcn_readlane(__float_as_int(l_hi), wl);
    const float la = __int_as_float((ibest & 1) ? hi_bits : lo_bits);
    if (lane == 0) {
        out_seq[r] = (s < KEEP) ? (float)ibest : 0.0f;
        out_lp[r] = la - __logf(se);
    }
}

extern "C" void kernel_launch(void* const* d_in, const int* in_sizes, int n_in,
                              void* d_out, int out_size, void* d_ws, size_t ws_size,
                              hipStream_t stream) {
    const int* tok      = (const int*)d_in[0];     // [256,1024] int32
    const float* conv_w = (const float*)d_in[1];   // [128,128,3] f32
    const float* conv_b = (const float*)d_in[2];   // [128] f32
    float* out_seq = (float*)d_out;                // 262144 (new_seq as f32)
    float* out_lp  = (float*)d_out + N_ROWS;       // 262144 (log_probs)

    const size_t wT_bytes = (size_t)3 * WT_ROWS * T_CH * sizeof(float);
    if (ws_size >= wT_bytes) {
        float* wT = (float*)d_ws;
        int n = 3 * WT_ROWS * T_CH;
        transpose_w_kernel<<<(n + 255) / 256, 256, 0, stream>>>(conv_w, conv_b, wT);
        seq_rewriter_kernel<<<N_BLOCKS, 256, 0, stream>>>(tok, wT, out_seq, out_lp);
    } else {
        seq_rewriter_fallback<<<N_ROWS / 4, 256, 0, stream>>>(
            tok, conv_w, conv_b, out_seq, out_lp);
    }
}